// Round 1
// baseline (535.062 us; speedup 1.0000x reference)
//
#include <hip/hip_runtime.h>

#define N 32
#define C 512
#define H 64
#define W 64
#define HW 4096
#define CB 32
#define NCHUNK 4
#define CCHUNK 128   // C / NCHUNK
#define EPS 1e-5f

// K1: partial attention logits. Each block: one n, one 1024-position hw tile,
// one 128-channel chunk. Coalesced float4 reads of x; partial sums to ws.
__global__ __launch_bounds__(256) void k1_logits_partial(
    const float* __restrict__ x, const float* __restrict__ wk_w,
    float* __restrict__ partial)
{
    const int tid   = threadIdx.x;
    const int tile  = blockIdx.x;   // 0..3
    const int chunk = blockIdx.y;   // 0..3
    const int n     = blockIdx.z;   // 0..31
    const int hw4   = tile * 256 + tid;          // float4 index within plane
    const float4* xb = (const float4*)(x + (size_t)n * C * HW);
    const int c0 = chunk * CCHUNK;
    float4 acc = make_float4(0.f, 0.f, 0.f, 0.f);
    #pragma unroll 4
    for (int c = 0; c < CCHUNK; ++c) {
        const float wv = wk_w[c0 + c];
        const float4 xv = xb[(size_t)(c0 + c) * (HW / 4) + hw4];
        acc.x += xv.x * wv; acc.y += xv.y * wv;
        acc.z += xv.z * wv; acc.w += xv.w * wv;
    }
    float4* pb = (float4*)(partial + (size_t)(n * NCHUNK + chunk) * HW);
    pb[hw4] = acc;
}

// K2: sum the 4 partials and softmax over H (axis=1) per (n,w) column.
// One wave per (n,w); lane = h (H == 64 == wavefront size).
__global__ __launch_bounds__(256) void k2_softmax(
    const float* __restrict__ partial, const float* __restrict__ wk_b,
    float* __restrict__ attn)
{
    const int tid  = threadIdx.x;
    const int lane = tid & 63;                       // h
    const int wid  = blockIdx.x * 4 + (tid >> 6);    // n*W + w
    const int n = wid >> 6;
    const int w = wid & 63;
    float l = wk_b[0];
    #pragma unroll
    for (int ch = 0; ch < NCHUNK; ++ch)
        l += partial[(size_t)(n * NCHUNK + ch) * HW + lane * W + w];
    float m = l;
    #pragma unroll
    for (int o = 32; o > 0; o >>= 1) m = fmaxf(m, __shfl_xor(m, o));
    const float e = __expf(l - m);
    float s = e;
    #pragma unroll
    for (int o = 32; o > 0; o >>= 1) s += __shfl_xor(s, o);
    attn[(size_t)n * HW + lane * W + w] = e / s;
}

// K3: ctx[n,c] = dot(x[n,c,:], attn[n,:]). One wave per (n,c);
// 16 coalesced float4 iterations + wave shuffle reduction.
__global__ __launch_bounds__(256) void k3_ctx(
    const float* __restrict__ x, const float* __restrict__ attn,
    float* __restrict__ ctx)
{
    const int tid  = threadIdx.x;
    const int lane = tid & 63;
    const int wid  = blockIdx.x * 4 + (tid >> 6);    // n*C + c
    const int n = wid >> 9;
    const float4* xr = (const float4*)(x + (size_t)wid * HW);
    const float4* ar = (const float4*)(attn + (size_t)n * HW);
    float acc = 0.f;
    #pragma unroll
    for (int i = 0; i < 16; ++i) {
        const float4 xv = xr[i * 64 + lane];
        const float4 av = ar[i * 64 + lane];
        acc += xv.x * av.x + xv.y * av.y + xv.z * av.z + xv.w * av.w;
    }
    #pragma unroll
    for (int o = 32; o > 0; o >>= 1) acc += __shfl_xor(acc, o);
    if (lane == 0) ctx[wid] = acc;
}

// K4: per-image bottleneck: v = ctx@wv1^T (512->32), LayerNorm, ReLU,
// out_vec = v@wv2^T (32->512). One block per n.
__global__ __launch_bounds__(256) void k4_bottleneck(
    const float* __restrict__ ctx, const float* __restrict__ wv1_w,
    const float* __restrict__ ln_g, const float* __restrict__ ln_b,
    const float* __restrict__ wv2_w, float* __restrict__ out_vec)
{
    __shared__ float ctx_s[C];
    __shared__ float v_s[CB];
    const int tid = threadIdx.x;
    const int n   = blockIdx.x;
    ctx_s[tid]       = ctx[n * C + tid];
    ctx_s[tid + 256] = ctx[n * C + tid + 256];
    __syncthreads();
    {   // 8 lanes per output channel b
        const int b = tid >> 3, sub = tid & 7;
        const float* wr = wv1_w + b * C;
        float s = 0.f;
        #pragma unroll 8
        for (int j = sub; j < C; j += 8) s += wr[j] * ctx_s[j];
        #pragma unroll
        for (int o = 4; o > 0; o >>= 1) s += __shfl_down(s, o, 8);
        if (sub == 0) v_s[b] = s;
    }
    __syncthreads();
    if (tid < CB) {  // LayerNorm over 32 channels in lanes 0..31 of wave 0
        const float val = v_s[tid];
        float sm = val, sq = val * val;
        #pragma unroll
        for (int o = 16; o > 0; o >>= 1) {
            sm += __shfl_xor(sm, o, 32);
            sq += __shfl_xor(sq, o, 32);
        }
        const float mu  = sm / CB;
        const float var = sq / CB - mu * mu;
        const float vh  = (val - mu) * rsqrtf(var + EPS) * ln_g[tid] + ln_b[tid];
        v_s[tid] = fmaxf(vh, 0.f);
    }
    __syncthreads();
    for (int c = tid; c < C; c += 256) {
        const float* w2 = wv2_w + c * CB;
        float a = 0.f;
        #pragma unroll
        for (int b = 0; b < CB; ++b) a += v_s[b] * w2[b];
        out_vec[n * C + c] = a;
    }
}

// K5: out = x + out_vec[n,c] broadcast. Pure float4 streaming pass.
__global__ __launch_bounds__(256) void k5_add(
    const float* __restrict__ x, const float* __restrict__ out_vec,
    float* __restrict__ out)
{
    const size_t i4 = (size_t)blockIdx.x * 256 + threadIdx.x;
    const int nc = (int)(i4 >> 10);                  // 1024 float4 per plane
    const float4 xv = ((const float4*)x)[i4];
    const float a = out_vec[nc];
    ((float4*)out)[i4] = make_float4(xv.x + a, xv.y + a, xv.z + a, xv.w + a);
}

extern "C" void kernel_launch(void* const* d_in, const int* in_sizes, int n_in,
                              void* d_out, int out_size, void* d_ws, size_t ws_size,
                              hipStream_t stream) {
    const float* x     = (const float*)d_in[0];
    const float* wk_w  = (const float*)d_in[1];
    const float* wk_b  = (const float*)d_in[2];
    const float* wv1_w = (const float*)d_in[3];
    const float* ln_g  = (const float*)d_in[4];
    const float* ln_b  = (const float*)d_in[5];
    const float* wv2_w = (const float*)d_in[6];
    float* out = (float*)d_out;

    float* ws      = (float*)d_ws;
    float* partial = ws;                                   // N*4*HW = 524288 f
    float* attn    = partial + (size_t)N * NCHUNK * HW;    // N*HW   = 131072 f
    float* ctx     = attn + (size_t)N * HW;                // N*C    =  16384 f
    float* ovec    = ctx + (size_t)N * C;                  // N*C    =  16384 f

    k1_logits_partial<<<dim3(4, 4, 32), 256, 0, stream>>>(x, wk_w, partial);
    k2_softmax<<<512, 256, 0, stream>>>(partial, wk_b, attn);
    k3_ctx<<<4096, 256, 0, stream>>>(x, attn, ctx);
    k4_bottleneck<<<32, 256, 0, stream>>>(ctx, wv1_w, ln_g, ln_b, wv2_w, ovec);
    k5_add<<<65536, 256, 0, stream>>>(x, ovec, out);
}